// Round 2
// baseline (486.329 us; speedup 1.0000x reference)
//
#include <hip/hip_runtime.h>
#include <math.h>

#define B_  2048
#define T_  200

typedef short short8 __attribute__((ext_vector_type(8)));
typedef float f32x4  __attribute__((ext_vector_type(4)));

__device__ __forceinline__ unsigned short f2bf_rne(float x) {
    unsigned u = __float_as_uint(x);
    unsigned r = u + 0x7FFFu + ((u >> 16) & 1u);
    return (unsigned short)(r >> 16);
}
__device__ __forceinline__ float bf2f(unsigned short h) {
    return __uint_as_float(((unsigned)h) << 16);
}
__device__ __forceinline__ void split2(float x, unsigned short& hi, unsigned short& lo) {
    hi = f2bf_rne(x); lo = f2bf_rne(x - bf2f(hi));
}

// One block (4 waves) per batch element b. Barrier-free 13-m-tile loop.
// This revision software-pipelines all global latency:
//   - k rows for tile mt+4 prefetched while computing tile mt (HBM ~900cyc hidden)
//   - a1/a2 epilogue coefficients prefetched one tile ahead into registers
//   - base1 computed with 3-way parallel coalesced partials (no serial 64-chain)
//   - v loads issued before the softmax barriers, consumed after
// VGPR grows (~84 -> ~150) deliberately: LDS caps occupancy at 3 blocks/CU
// either way (launch_bounds(256,3) allows 170 VGPR).
__global__ __launch_bounds__(256, 3)
void att_kernel(const float* __restrict__ q,
                const float* __restrict__ k,
                const float* __restrict__ v,
                const float* __restrict__ W1,
                const float* __restrict__ b1,
                const float* __restrict__ a1,
                const float* __restrict__ W2,
                const float* __restrict__ b2,
                const float* __restrict__ a2,
                const float* __restrict__ Wf,
                const float* __restrict__ bf,
                float* __restrict__ out)
{
    const int b    = blockIdx.x;
    const int tid  = threadIdx.x;
    const int lane = tid & 63;
    const int wv   = __builtin_amdgcn_readfirstlane(tid >> 6);
    const int ncl  = lane & 15;
    const int q4   = lane >> 4;
    const int kq   = q4 * 8;

    __shared__ unsigned short s_wqhi[80 * 72];               // 11.5 KB
    __shared__ unsigned short s_wqlo[80 * 72];               // 11.5 KB
    __shared__ __align__(16) unsigned short s_h1[2 * 64 * 104]; // 26 KB, unioned
    __shared__ float s_q[64];
    __shared__ float s_b1p[240];                             // base1 partials
    __shared__ float s_logits[256];

    unsigned short* s_h1hi = s_h1;
    unsigned short* s_h1lo = s_h1 + 64 * 104;
    // softmax/v-sum scratch aliases s_h1 (dead after the tile loop):
    float*  u_w   = (float*)s_h1;                 // [256]  bytes 0..1023
    float4* u_acc = (float4*)(s_h1 + 512);        // [256]  bytes 1024..5119
    float*  u_red = (float*)(s_h1 + 2560);        // [8]    bytes 5120..5151

    const float* kb = k + (size_t)b * T_ * 64;
    const float* vb = v + (size_t)b * T_ * 64;

    // ---- tile-0 prefetch: k rows (HBM-cold) + a1/a2 epilogue slices (L2-hot).
    // First tiles are mt = wv < 4, so all t-indices < 64 < T_ (no clamps needed).
    float4 pk0, pk1, pk2, pk3;
    float  pa1[5][4];
    float  pa2[3][4];
    {
        const int trow = wv * 16 + ncl;
        const float4* kr = (const float4*)(kb + trow * 64);
        pk0 = kr[q4 * 2];     pk1 = kr[q4 * 2 + 1];
        pk2 = kr[8 + q4 * 2]; pk3 = kr[8 + q4 * 2 + 1];
        #pragma unroll
        for (int nt = 0; nt < 5; ++nt) {
            #pragma unroll
            for (int r = 0; r < 4; ++r) {
                const int t = wv * 16 + q4 * 4 + r;
                pa1[nt][r] = a1[t * 80 + nt * 16 + ncl];
            }
        }
        #pragma unroll
        for (int nt = 0; nt < 3; ++nt) {
            const int n2 = nt * 16 + ncl;
            #pragma unroll
            for (int r = 0; r < 4; ++r) {
                const int t = wv * 16 + q4 * 4 + r;
                pa2[nt][r] = (n2 < 40) ? a2[t * 40 + n2] : 0.f;
            }
        }
    }

    if (tid < 64) s_q[tid] = q[b * 64 + tid];
    __syncthreads();

    // ---- prologue: per-b wq (split bf16, B-layout [j][kk]), base1 partials, h1 k-pad
    for (int idx = tid; idx < 5120; idx += 256) {
        const int kk = idx / 80, j = idx - kk * 80;
        const float x = W1[5120 + idx] - W1[10240 + idx] + s_q[kk] * W1[15360 + idx];
        unsigned short hi, lo; split2(x, hi, lo);
        s_wqhi[j * 72 + kk] = hi;
        s_wqlo[j * 72 + kk] = lo;
    }
    // base1 partials: 3 parallel k-chunks, coalesced over j (lanes = consecutive j)
    if (tid < 240) {
        const int part = tid / 80;
        const int j    = tid - part * 80;
        const int k0   = (part == 0) ? 0  : (part == 1 ? 22 : 43);
        const int k1   = (part == 0) ? 22 : (part == 1 ? 43 : 64);
        float s = 0.f;
        for (int i = k0; i < k1; ++i)
            s += s_q[i] * (W1[i * 80 + j] + W1[10240 + i * 80 + j]);
        s_b1p[tid] = s;
    }
    for (int idx = tid; idx < 1024; idx += 256) {   // zero h1 cols 80..95 (K-pad)
        const int r = idx >> 4, c = 80 + (idx & 15);
        s_h1hi[r * 104 + c] = 0;
        s_h1lo[r * 104 + c] = 0;
    }
    __syncthreads();

    // ---- hoist W2 B-fragments into registers (built from L2, once per block)
    short8 w2h[3][3], w2l[3][3];
    #pragma unroll
    for (int nt = 0; nt < 3; ++nt) {
        const int n = nt * 16 + ncl;
        #pragma unroll
        for (int c = 0; c < 3; ++c) {
            short8 hh, ll;
            #pragma unroll
            for (int jj = 0; jj < 8; ++jj) {
                const int kk = c * 32 + kq + jj;
                const float x = (kk < 80 && n < 40) ? W2[kk * 40 + n] : 0.f;
                unsigned short hi, lo; split2(x, hi, lo);
                hh[jj] = (short)hi; ll[jj] = (short)lo;
            }
            w2h[nt][c] = hh; w2l[nt][c] = ll;
        }
    }
    float wf3[3], b23[3], bb1[5];
    #pragma unroll
    for (int nt = 0; nt < 3; ++nt) {
        const int n = nt * 16 + ncl;
        wf3[nt] = (n < 40) ? Wf[n] : 0.f;
        b23[nt] = (n < 40) ? b2[n] : 0.f;
    }
    #pragma unroll
    for (int nt = 0; nt < 5; ++nt) {
        const int n = nt * 16 + ncl;
        bb1[nt] = b1[n] + s_b1p[n] + s_b1p[80 + n] + s_b1p[160 + n];
    }
    const float bfv = bf[0];

    // ---- barrier-free tile loop: wave wv owns m-tiles wv, wv+4, wv+8, wv+12
    const int h1row = (wv * 16 + ncl) * 104;
    for (int mt = wv; mt < 13; mt += 4) {
        // consume prefetched k -> A-fragments (split bf16); waits on last issue
        const float a0v[8] = {pk0.x, pk0.y, pk0.z, pk0.w, pk1.x, pk1.y, pk1.z, pk1.w};
        const float a1v[8] = {pk2.x, pk2.y, pk2.z, pk2.w, pk3.x, pk3.y, pk3.z, pk3.w};
        short8 ahi0, alo0, ahi1, alo1;
        #pragma unroll
        for (int jj = 0; jj < 8; ++jj) {
            unsigned short h, l;
            split2(a0v[jj], h, l); ahi0[jj] = (short)h; alo0[jj] = (short)l;
            split2(a1v[jj], h, l); ahi1[jj] = (short)h; alo1[jj] = (short)l;
        }

        // issue next-tile k loads now: ~full tile of compute to hide HBM latency
        const int mtn = mt + 4;
        if (mtn < 13) {
            const int trow = mtn * 16 + ncl;
            if (trow < T_) {
                const float4* kr = (const float4*)(kb + trow * 64);
                pk0 = kr[q4 * 2];     pk1 = kr[q4 * 2 + 1];
                pk2 = kr[8 + q4 * 2]; pk3 = kr[8 + q4 * 2 + 1];
            } else {
                pk0 = make_float4(0.f, 0.f, 0.f, 0.f);
                pk1 = pk0; pk2 = pk0; pk3 = pk0;
            }
        }

        // Dense1 MFMA + PReLU1 epilogue -> h1 (wave-local LDS round-trip)
        #pragma unroll
        for (int nt = 0; nt < 5; ++nt) {
            const int n = nt * 16 + ncl;
            const short8 bhi0 = *(const short8*)&s_wqhi[n * 72 + kq];
            const short8 bhi1 = *(const short8*)&s_wqhi[n * 72 + 32 + kq];
            const short8 blo0 = *(const short8*)&s_wqlo[n * 72 + kq];
            const short8 blo1 = *(const short8*)&s_wqlo[n * 72 + 32 + kq];
            f32x4 acc = {0.f, 0.f, 0.f, 0.f};
            acc = __builtin_amdgcn_mfma_f32_16x16x32_bf16(ahi0, blo0, acc, 0, 0, 0);
            acc = __builtin_amdgcn_mfma_f32_16x16x32_bf16(alo0, bhi0, acc, 0, 0, 0);
            acc = __builtin_amdgcn_mfma_f32_16x16x32_bf16(ahi1, blo1, acc, 0, 0, 0);
            acc = __builtin_amdgcn_mfma_f32_16x16x32_bf16(alo1, bhi1, acc, 0, 0, 0);
            acc = __builtin_amdgcn_mfma_f32_16x16x32_bf16(ahi0, bhi0, acc, 0, 0, 0);
            acc = __builtin_amdgcn_mfma_f32_16x16x32_bf16(ahi1, bhi1, acc, 0, 0, 0);
            #pragma unroll
            for (int r = 0; r < 4; ++r) {
                const int rloc = q4 * 4 + r;
                float x = acc[r] + bb1[nt];
                const float al = pa1[nt][r];
                x = x > 0.f ? x : al * x;
                unsigned short hi, lo; split2(x, hi, lo);
                s_h1hi[(wv * 16 + rloc) * 104 + n] = hi;
                s_h1lo[(wv * 16 + rloc) * 104 + n] = lo;
            }
        }

        // Dense2 MFMA (W2 frags in regs) + PReLU2*Wf epilogue -> logits
        short8 ah[3], al[3];
        #pragma unroll
        for (int c = 0; c < 3; ++c) {
            ah[c] = *(const short8*)&s_h1hi[h1row + c * 32 + kq];
            al[c] = *(const short8*)&s_h1lo[h1row + c * 32 + kq];
        }
        float part[4] = {0.f, 0.f, 0.f, 0.f};
        #pragma unroll
        for (int nt = 0; nt < 3; ++nt) {
            f32x4 acc = {0.f, 0.f, 0.f, 0.f};
            #pragma unroll
            for (int c = 0; c < 3; ++c) {
                acc = __builtin_amdgcn_mfma_f32_16x16x32_bf16(ah[c], w2l[nt][c], acc, 0, 0, 0);
                acc = __builtin_amdgcn_mfma_f32_16x16x32_bf16(al[c], w2h[nt][c], acc, 0, 0, 0);
                acc = __builtin_amdgcn_mfma_f32_16x16x32_bf16(ah[c], w2h[nt][c], acc, 0, 0, 0);
            }
            #pragma unroll
            for (int r = 0; r < 4; ++r) {
                float x = acc[r] + b23[nt];
                const float al2 = pa2[nt][r];
                x = x > 0.f ? x : al2 * x;
                part[r] += x * wf3[nt];
            }
        }
        #pragma unroll
        for (int r = 0; r < 4; ++r) {
            float p = part[r];
            p += __shfl_xor(p, 1, 64);
            p += __shfl_xor(p, 2, 64);
            p += __shfl_xor(p, 4, 64);
            p += __shfl_xor(p, 8, 64);
            part[r] = p;
        }
        if (ncl == 0) {
            #pragma unroll
            for (int r = 0; r < 4; ++r) {
                const int t = mt * 16 + q4 * 4 + r;
                if (t < T_) s_logits[t] = part[r] + bfv;
            }
        }

        // issue next-tile a1/a2 prefetch (consumed above, safe to overwrite)
        if (mtn < 13) {
            #pragma unroll
            for (int nt = 0; nt < 5; ++nt) {
                #pragma unroll
                for (int r = 0; r < 4; ++r) {
                    int t = mtn * 16 + q4 * 4 + r; if (t > T_ - 1) t = T_ - 1;
                    pa1[nt][r] = a1[t * 80 + nt * 16 + ncl];
                }
            }
            #pragma unroll
            for (int nt = 0; nt < 3; ++nt) {
                const int n2 = nt * 16 + ncl;
                #pragma unroll
                for (int r = 0; r < 4; ++r) {
                    int t = mtn * 16 + q4 * 4 + r; if (t > T_ - 1) t = T_ - 1;
                    pa2[nt][r] = (n2 < 40) ? a2[t * 40 + n2] : 0.f;
                }
            }
        }
    }
    __syncthreads();   // logits complete; s_h1 dead -> scratch reuse OK

    // ---- issue all v loads NOW so they land during the softmax barriers
    const int c4 = tid & 15, g = tid >> 4;
    const float4* vb4 = (const float4*)vb;
    float4 pv[13];
    #pragma unroll
    for (int i = 0; i < 13; ++i) {
        int t = g + i * 16; if (t > T_ - 1) t = T_ - 1;
        pv[i] = vb4[t * 16 + c4];
    }

    // ---- softmax over 200 logits (wave shuffles, 2 barriers)
    float logit = -INFINITY;
    if (tid < T_) logit = s_logits[tid];
    float mred = logit;
    #pragma unroll
    for (int off = 1; off < 64; off <<= 1) mred = fmaxf(mred, __shfl_xor(mred, off, 64));
    if (lane == 0) u_red[wv] = mred;
    __syncthreads();
    const float mx = fmaxf(fmaxf(u_red[0], u_red[1]), fmaxf(u_red[2], u_red[3]));
    const float ew = (tid < T_) ? __expf(logit - mx) : 0.f;
    float ssum = ew;
    #pragma unroll
    for (int off = 1; off < 64; off <<= 1) ssum += __shfl_xor(ssum, off, 64);
    if (lane == 0) u_red[4 + wv] = ssum;
    __syncthreads();
    const float tot = (u_red[4] + u_red[5]) + (u_red[6] + u_red[7]);
    const float inv = 1.0f / tot;
    u_w[tid] = ew * inv;
    __syncthreads();

    // ---- out[b][d] = sum_t w_t * v[b][t][d]  (prefetched float4 lanes)
    float4 acc4 = {0.f, 0.f, 0.f, 0.f};
    #pragma unroll
    for (int i = 0; i < 13; ++i) {
        const int t = g + i * 16;
        const float wt = (t < T_) ? u_w[t] : 0.f;
        acc4.x += wt * pv[i].x; acc4.y += wt * pv[i].y;
        acc4.z += wt * pv[i].z; acc4.w += wt * pv[i].w;
    }
    u_acc[tid] = acc4;
    __syncthreads();
    if (tid < 64) {
        const float* uf = (const float*)u_acc;
        float s = 0.f;
        #pragma unroll
        for (int gg = 0; gg < 16; ++gg) s += uf[gg * 64 + tid];
        out[b * 64 + tid] = s;
    }
}

extern "C" void kernel_launch(void* const* d_in, const int* in_sizes, int n_in,
                              void* d_out, int out_size, void* d_ws, size_t ws_size,
                              hipStream_t stream) {
    const float* q  = (const float*)d_in[0];
    const float* k  = (const float*)d_in[1];
    const float* v  = (const float*)d_in[2];
    const float* W1 = (const float*)d_in[3];
    const float* b1 = (const float*)d_in[4];
    const float* a1 = (const float*)d_in[5];
    const float* W2 = (const float*)d_in[6];
    const float* b2 = (const float*)d_in[7];
    const float* a2 = (const float*)d_in[8];
    const float* Wf = (const float*)d_in[9];
    const float* bf = (const float*)d_in[10];
    float* out = (float*)d_out;

    hipLaunchKernelGGL(att_kernel, dim3(B_), dim3(256), 0, stream,
                       q, k, v, W1, b1, a1, W2, b2, a2, Wf, bf, out);
}

// Round 4
// 374.733 us; speedup vs baseline: 1.2978x; 1.2978x over previous
//
#include <hip/hip_runtime.h>
#include <math.h>

#define B_  2048
#define T_  200

typedef short short8 __attribute__((ext_vector_type(8)));
typedef float f32x4  __attribute__((ext_vector_type(4)));

__device__ __forceinline__ unsigned short f2bf_rne(float x) {
    unsigned u = __float_as_uint(x);
    unsigned r = u + 0x7FFFu + ((u >> 16) & 1u);
    return (unsigned short)(r >> 16);
}
__device__ __forceinline__ float bf2f(unsigned short h) {
    return __uint_as_float(((unsigned)h) << 16);
}
__device__ __forceinline__ void split2(float x, unsigned short& hi, unsigned short& lo) {
    hi = f2bf_rne(x); lo = f2bf_rne(x - bf2f(hi));
}

// One block (4 waves) per batch element b. Barrier-free 13-m-tile loop.
// Latency-hiding rules learned from the R1 spill disaster (WRITE_SIZE 56->333MB):
//   - loop-carried prefetch state is ONLY named scalar float4s (pk0..pk3),
//     written UNCONDITIONALLY (clamped address, never a conditional write)
//   - a1/a2 coefficient loads are hoisted to the TOP of the current iteration
//     into arrays that live entirely inside one iteration (SROA-safe)
//   - v-phase is a fixed 13-trip unrolled loop after the last barrier: all 13
//     independent global loads issue together, no across-barrier arrays
__global__ __launch_bounds__(256, 3)
void att_kernel(const float* __restrict__ q,
                const float* __restrict__ k,
                const float* __restrict__ v,
                const float* __restrict__ W1,
                const float* __restrict__ b1,
                const float* __restrict__ a1,
                const float* __restrict__ W2,
                const float* __restrict__ b2,
                const float* __restrict__ a2,
                const float* __restrict__ Wf,
                const float* __restrict__ bf,
                float* __restrict__ out)
{
    const int b    = blockIdx.x;
    const int tid  = threadIdx.x;
    const int lane = tid & 63;
    const int wv   = __builtin_amdgcn_readfirstlane(tid >> 6);
    const int ncl  = lane & 15;
    const int q4   = lane >> 4;
    const int kq   = q4 * 8;

    __shared__ unsigned short s_wqhi[80 * 72];               // 11.5 KB
    __shared__ unsigned short s_wqlo[80 * 72];               // 11.5 KB
    __shared__ __align__(16) unsigned short s_h1[2 * 64 * 104]; // 26 KB, unioned
    __shared__ float s_q[64];
    __shared__ float s_b1p[240];                             // base1 partials
    __shared__ float s_logits[256];

    unsigned short* s_h1hi = s_h1;
    unsigned short* s_h1lo = s_h1 + 64 * 104;
    // softmax/v-sum scratch aliases s_h1 (dead after the tile loop):
    float*  u_w   = (float*)s_h1;                 // [256]  bytes 0..1023
    float4* u_acc = (float4*)(s_h1 + 512);        // [256]  bytes 1024..5119
    float*  u_red = (float*)(s_h1 + 2560);        // [8]    bytes 5120..5151

    const float* kb = k + (size_t)b * T_ * 64;
    const float* vb = v + (size_t)b * T_ * 64;

    // ---- first-tile k prefetch (HBM-cold): issued before the prologue so the
    // W1-prep work hides the latency. First tiles are mt = wv < 4 -> trow < 64.
    float4 pk0, pk1, pk2, pk3;
    {
        const float4* kr = (const float4*)(kb + (wv * 16 + ncl) * 64);
        pk0 = kr[q4 * 2];     pk1 = kr[q4 * 2 + 1];
        pk2 = kr[8 + q4 * 2]; pk3 = kr[8 + q4 * 2 + 1];
    }

    if (tid < 64) s_q[tid] = q[b * 64 + tid];
    __syncthreads();

    // ---- prologue: per-b wq (split bf16, B-layout [j][kk]), base1 partials, h1 k-pad
    for (int idx = tid; idx < 5120; idx += 256) {
        const int kk = idx / 80, j = idx - kk * 80;
        const float x = W1[5120 + idx] - W1[10240 + idx] + s_q[kk] * W1[15360 + idx];
        unsigned short hi, lo; split2(x, hi, lo);
        s_wqhi[j * 72 + kk] = hi;
        s_wqlo[j * 72 + kk] = lo;
    }
    // base1 partials: 3 parallel k-chunks, coalesced over j (lanes = consecutive j)
    if (tid < 240) {
        const int part = tid / 80;
        const int j    = tid - part * 80;
        const int k0   = (part == 0) ? 0  : (part == 1 ? 22 : 43);
        const int k1   = (part == 0) ? 22 : (part == 1 ? 43 : 64);
        float s = 0.f;
        for (int i = k0; i < k1; ++i)
            s += s_q[i] * (W1[i * 80 + j] + W1[10240 + i * 80 + j]);
        s_b1p[tid] = s;
    }
    for (int idx = tid; idx < 1024; idx += 256) {   // zero h1 cols 80..95 (K-pad)
        const int r = idx >> 4, c = 80 + (idx & 15);
        s_h1hi[r * 104 + c] = 0;
        s_h1lo[r * 104 + c] = 0;
    }
    __syncthreads();

    // ---- hoist W2 B-fragments into registers (built from L2, once per block)
    short8 w2h[3][3], w2l[3][3];
    #pragma unroll
    for (int nt = 0; nt < 3; ++nt) {
        const int n = nt * 16 + ncl;
        #pragma unroll
        for (int c = 0; c < 3; ++c) {
            short8 hh, ll;
            #pragma unroll
            for (int jj = 0; jj < 8; ++jj) {
                const int kk = c * 32 + kq + jj;
                const float x = (kk < 80 && n < 40) ? W2[kk * 40 + n] : 0.f;
                unsigned short hi, lo; split2(x, hi, lo);
                hh[jj] = (short)hi; ll[jj] = (short)lo;
            }
            w2h[nt][c] = hh; w2l[nt][c] = ll;
        }
    }
    float wf3[3], b23[3], bb1[5];
    #pragma unroll
    for (int nt = 0; nt < 3; ++nt) {
        const int n = nt * 16 + ncl;
        wf3[nt] = (n < 40) ? Wf[n] : 0.f;
        b23[nt] = (n < 40) ? b2[n] : 0.f;
    }
    #pragma unroll
    for (int nt = 0; nt < 5; ++nt) {
        const int n = nt * 16 + ncl;
        bb1[nt] = b1[n] + s_b1p[n] + s_b1p[80 + n] + s_b1p[160 + n];
    }
    const float bfv = bf[0];

    // ---- barrier-free tile loop: wave wv owns m-tiles wv, wv+4, wv+8, wv+12
    const int h1row = (wv * 16 + ncl) * 104;
    for (int mt = wv; mt < 13; mt += 4) {
        // current-tile a1/a2 coefficient loads issued FIRST (L2-hot ~200cyc);
        // consumed in the epilogues below -> ~one MFMA pass of slack.
        float ca1[5][4];
        #pragma unroll
        for (int nt = 0; nt < 5; ++nt) {
            #pragma unroll
            for (int r = 0; r < 4; ++r) {
                int t = mt * 16 + q4 * 4 + r; if (t > T_ - 1) t = T_ - 1;
                ca1[nt][r] = a1[t * 80 + nt * 16 + ncl];
            }
        }
        float ca2[3][4];
        #pragma unroll
        for (int nt = 0; nt < 3; ++nt) {
            const int n2 = nt * 16 + ncl;
            #pragma unroll
            for (int r = 0; r < 4; ++r) {
                int t = mt * 16 + q4 * 4 + r; if (t > T_ - 1) t = T_ - 1;
                ca2[nt][r] = (n2 < 40) ? a2[t * 40 + n2] : 0.f;
            }
        }

        // consume prefetched k -> A-fragments (split bf16)
        const float a0v[8] = {pk0.x, pk0.y, pk0.z, pk0.w, pk1.x, pk1.y, pk1.z, pk1.w};
        const float a1v[8] = {pk2.x, pk2.y, pk2.z, pk2.w, pk3.x, pk3.y, pk3.z, pk3.w};
        short8 ahi0, alo0, ahi1, alo1;
        #pragma unroll
        for (int jj = 0; jj < 8; ++jj) {
            unsigned short h, l;
            split2(a0v[jj], h, l); ahi0[jj] = (short)h; alo0[jj] = (short)l;
            split2(a1v[jj], h, l); ahi1[jj] = (short)h; alo1[jj] = (short)l;
        }

        // issue next-tile k loads UNCONDITIONALLY (clamped row; the extra load
        // on the last iteration is a harmless L2 hit). Named scalars -> SSA.
        {
            int trow_n = (mt + 4) * 16 + ncl; if (trow_n > T_ - 1) trow_n = T_ - 1;
            const float4* kr = (const float4*)(kb + trow_n * 64);
            pk0 = kr[q4 * 2];     pk1 = kr[q4 * 2 + 1];
            pk2 = kr[8 + q4 * 2]; pk3 = kr[8 + q4 * 2 + 1];
        }

        // Dense1 MFMA + PReLU1 epilogue -> h1 (wave-local LDS round-trip)
        #pragma unroll
        for (int nt = 0; nt < 5; ++nt) {
            const int n = nt * 16 + ncl;
            const short8 bhi0 = *(const short8*)&s_wqhi[n * 72 + kq];
            const short8 bhi1 = *(const short8*)&s_wqhi[n * 72 + 32 + kq];
            const short8 blo0 = *(const short8*)&s_wqlo[n * 72 + kq];
            const short8 blo1 = *(const short8*)&s_wqlo[n * 72 + 32 + kq];
            f32x4 acc = {0.f, 0.f, 0.f, 0.f};
            acc = __builtin_amdgcn_mfma_f32_16x16x32_bf16(ahi0, blo0, acc, 0, 0, 0);
            acc = __builtin_amdgcn_mfma_f32_16x16x32_bf16(alo0, bhi0, acc, 0, 0, 0);
            acc = __builtin_amdgcn_mfma_f32_16x16x32_bf16(ahi1, blo1, acc, 0, 0, 0);
            acc = __builtin_amdgcn_mfma_f32_16x16x32_bf16(alo1, bhi1, acc, 0, 0, 0);
            acc = __builtin_amdgcn_mfma_f32_16x16x32_bf16(ahi0, bhi0, acc, 0, 0, 0);
            acc = __builtin_amdgcn_mfma_f32_16x16x32_bf16(ahi1, bhi1, acc, 0, 0, 0);
            #pragma unroll
            for (int r = 0; r < 4; ++r) {
                const int rloc = q4 * 4 + r;
                float x = acc[r] + bb1[nt];
                const float al = ca1[nt][r];
                x = x > 0.f ? x : al * x;
                unsigned short hi, lo; split2(x, hi, lo);
                s_h1hi[(wv * 16 + rloc) * 104 + n] = hi;
                s_h1lo[(wv * 16 + rloc) * 104 + n] = lo;
            }
        }

        // Dense2 MFMA (W2 frags in regs) + PReLU2*Wf epilogue -> logits
        short8 ah[3], al[3];
        #pragma unroll
        for (int c = 0; c < 3; ++c) {
            ah[c] = *(const short8*)&s_h1hi[h1row + c * 32 + kq];
            al[c] = *(const short8*)&s_h1lo[h1row + c * 32 + kq];
        }
        float part[4] = {0.f, 0.f, 0.f, 0.f};
        #pragma unroll
        for (int nt = 0; nt < 3; ++nt) {
            f32x4 acc = {0.f, 0.f, 0.f, 0.f};
            #pragma unroll
            for (int c = 0; c < 3; ++c) {
                acc = __builtin_amdgcn_mfma_f32_16x16x32_bf16(ah[c], w2l[nt][c], acc, 0, 0, 0);
                acc = __builtin_amdgcn_mfma_f32_16x16x32_bf16(al[c], w2h[nt][c], acc, 0, 0, 0);
                acc = __builtin_amdgcn_mfma_f32_16x16x32_bf16(ah[c], w2h[nt][c], acc, 0, 0, 0);
            }
            #pragma unroll
            for (int r = 0; r < 4; ++r) {
                float x = acc[r] + b23[nt];
                const float al2 = ca2[nt][r];
                x = x > 0.f ? x : al2 * x;
                part[r] += x * wf3[nt];
            }
        }
        #pragma unroll
        for (int r = 0; r < 4; ++r) {
            float p = part[r];
            p += __shfl_xor(p, 1, 64);
            p += __shfl_xor(p, 2, 64);
            p += __shfl_xor(p, 4, 64);
            p += __shfl_xor(p, 8, 64);
            part[r] = p;
        }
        if (ncl == 0) {
            #pragma unroll
            for (int r = 0; r < 4; ++r) {
                const int t = mt * 16 + q4 * 4 + r;
                if (t < T_) s_logits[t] = part[r] + bfv;
            }
        }
    }
    __syncthreads();   // logits complete; s_h1 dead -> scratch reuse OK

    // ---- softmax over 200 logits (wave shuffles, 2 barriers)
    float logit = -INFINITY;
    if (tid < T_) logit = s_logits[tid];
    float mred = logit;
    #pragma unroll
    for (int off = 1; off < 64; off <<= 1) mred = fmaxf(mred, __shfl_xor(mred, off, 64));
    if (lane == 0) u_red[wv] = mred;
    __syncthreads();
    const float mx = fmaxf(fmaxf(u_red[0], u_red[1]), fmaxf(u_red[2], u_red[3]));
    const float ew = (tid < T_) ? __expf(logit - mx) : 0.f;
    float ssum = ew;
    #pragma unroll
    for (int off = 1; off < 64; off <<= 1) ssum += __shfl_xor(ssum, off, 64);
    if (lane == 0) u_red[4 + wv] = ssum;
    __syncthreads();
    const float tot = (u_red[4] + u_red[5]) + (u_red[6] + u_red[7]);
    const float inv = 1.0f / tot;
    u_w[tid] = ew * inv;
    __syncthreads();

    // ---- out[b][d] = sum_t w_t * v[b][t][d]
    // fixed 13-trip unrolled loop: all 13 independent global loads can issue
    // together (single latency), u_w reads are LDS-hot. No cross-barrier state.
    const int c4 = tid & 15, g = tid >> 4;
    const float4* vb4 = (const float4*)vb;
    float4 acc4 = {0.f, 0.f, 0.f, 0.f};
    #pragma unroll
    for (int i = 0; i < 13; ++i) {
        const int t = g + i * 16;
        const int tc = (t > T_ - 1) ? (T_ - 1) : t;
        const float wt = (t < T_) ? u_w[t] : 0.f;
        const float4 vv = vb4[tc * 16 + c4];
        acc4.x += wt * vv.x; acc4.y += wt * vv.y;
        acc4.z += wt * vv.z; acc4.w += wt * vv.w;
    }
    u_acc[tid] = acc4;
    __syncthreads();
    if (tid < 64) {
        const float* uf = (const float*)u_acc;
        float s = 0.f;
        #pragma unroll
        for (int gg = 0; gg < 16; ++gg) s += uf[gg * 64 + tid];
        out[b * 64 + tid] = s;
    }
}

extern "C" void kernel_launch(void* const* d_in, const int* in_sizes, int n_in,
                              void* d_out, int out_size, void* d_ws, size_t ws_size,
                              hipStream_t stream) {
    const float* q  = (const float*)d_in[0];
    const float* k  = (const float*)d_in[1];
    const float* v  = (const float*)d_in[2];
    const float* W1 = (const float*)d_in[3];
    const float* b1 = (const float*)d_in[4];
    const float* a1 = (const float*)d_in[5];
    const float* W2 = (const float*)d_in[6];
    const float* b2 = (const float*)d_in[7];
    const float* a2 = (const float*)d_in[8];
    const float* Wf = (const float*)d_in[9];
    const float* bf = (const float*)d_in[10];
    float* out = (float*)d_out;

    hipLaunchKernelGGL(att_kernel, dim3(B_), dim3(256), 0, stream,
                       q, k, v, W1, b1, a1, W2, b2, a2, Wf, bf, out);
}

// Round 5
// 300.734 us; speedup vs baseline: 1.6171x; 1.2461x over previous
//
#include <hip/hip_runtime.h>
#include <math.h>

#define B_  2048
#define T_  200

typedef short short8 __attribute__((ext_vector_type(8)));
typedef float f32x4  __attribute__((ext_vector_type(4)));

__device__ __forceinline__ unsigned short f2bf_rne(float x) {
    unsigned u = __float_as_uint(x);
    unsigned r = u + 0x7FFFu + ((u >> 16) & 1u);
    return (unsigned short)(r >> 16);
}
__device__ __forceinline__ float bf2f(unsigned short h) {
    return __uint_as_float(((unsigned)h) << 16);
}
__device__ __forceinline__ void split2(float x, unsigned short& hi, unsigned short& lo) {
    hi = f2bf_rne(x); lo = f2bf_rne(x - bf2f(hi));
}

// One block (4 waves) per batch element b. Barrier-free 13-m-tile loop.
// R5 = R4 with ONE change: __launch_bounds__(256,3) -> (256,2).
// Evidence: VGPR_Count pinned at 84 across all variants while WRITE_SIZE shows
// 55-150MB of scratch spill (output is only 0.5MB). The allocator splits the
// unified VGPR file (~84 arch + ~84 acc = 168 ~ 512/3 budget) and spills all
// extra float state. (256,2) doubles the budget to 256; LDS (51.7KB -> 3
// blocks/CU) stays the occupancy cap if the allocator lands <=170.
__global__ __launch_bounds__(256, 2)
void att_kernel(const float* __restrict__ q,
                const float* __restrict__ k,
                const float* __restrict__ v,
                const float* __restrict__ W1,
                const float* __restrict__ b1,
                const float* __restrict__ a1,
                const float* __restrict__ W2,
                const float* __restrict__ b2,
                const float* __restrict__ a2,
                const float* __restrict__ Wf,
                const float* __restrict__ bf,
                float* __restrict__ out)
{
    const int b    = blockIdx.x;
    const int tid  = threadIdx.x;
    const int lane = tid & 63;
    const int wv   = __builtin_amdgcn_readfirstlane(tid >> 6);
    const int ncl  = lane & 15;
    const int q4   = lane >> 4;
    const int kq   = q4 * 8;

    __shared__ unsigned short s_wqhi[80 * 72];               // 11.5 KB
    __shared__ unsigned short s_wqlo[80 * 72];               // 11.5 KB
    __shared__ __align__(16) unsigned short s_h1[2 * 64 * 104]; // 26 KB, unioned
    __shared__ float s_q[64];
    __shared__ float s_b1p[240];                             // base1 partials
    __shared__ float s_logits[256];

    unsigned short* s_h1hi = s_h1;
    unsigned short* s_h1lo = s_h1 + 64 * 104;
    // softmax/v-sum scratch aliases s_h1 (dead after the tile loop):
    float*  u_w   = (float*)s_h1;                 // [256]  bytes 0..1023
    float4* u_acc = (float4*)(s_h1 + 512);        // [256]  bytes 1024..5119
    float*  u_red = (float*)(s_h1 + 2560);        // [8]    bytes 5120..5151

    const float* kb = k + (size_t)b * T_ * 64;
    const float* vb = v + (size_t)b * T_ * 64;

    // ---- first-tile k prefetch (HBM-cold): issued before the prologue so the
    // W1-prep work hides the latency. First tiles are mt = wv < 4 -> trow < 64.
    float4 pk0, pk1, pk2, pk3;
    {
        const float4* kr = (const float4*)(kb + (wv * 16 + ncl) * 64);
        pk0 = kr[q4 * 2];     pk1 = kr[q4 * 2 + 1];
        pk2 = kr[8 + q4 * 2]; pk3 = kr[8 + q4 * 2 + 1];
    }

    if (tid < 64) s_q[tid] = q[b * 64 + tid];
    __syncthreads();

    // ---- prologue: per-b wq (split bf16, B-layout [j][kk]), base1 partials, h1 k-pad
    for (int idx = tid; idx < 5120; idx += 256) {
        const int kk = idx / 80, j = idx - kk * 80;
        const float x = W1[5120 + idx] - W1[10240 + idx] + s_q[kk] * W1[15360 + idx];
        unsigned short hi, lo; split2(x, hi, lo);
        s_wqhi[j * 72 + kk] = hi;
        s_wqlo[j * 72 + kk] = lo;
    }
    // base1 partials: 3 parallel k-chunks, coalesced over j (lanes = consecutive j)
    if (tid < 240) {
        const int part = tid / 80;
        const int j    = tid - part * 80;
        const int k0   = (part == 0) ? 0  : (part == 1 ? 22 : 43);
        const int k1   = (part == 0) ? 22 : (part == 1 ? 43 : 64);
        float s = 0.f;
        for (int i = k0; i < k1; ++i)
            s += s_q[i] * (W1[i * 80 + j] + W1[10240 + i * 80 + j]);
        s_b1p[tid] = s;
    }
    for (int idx = tid; idx < 1024; idx += 256) {   // zero h1 cols 80..95 (K-pad)
        const int r = idx >> 4, c = 80 + (idx & 15);
        s_h1hi[r * 104 + c] = 0;
        s_h1lo[r * 104 + c] = 0;
    }
    __syncthreads();

    // ---- hoist W2 B-fragments into registers (built from L2, once per block)
    short8 w2h[3][3], w2l[3][3];
    #pragma unroll
    for (int nt = 0; nt < 3; ++nt) {
        const int n = nt * 16 + ncl;
        #pragma unroll
        for (int c = 0; c < 3; ++c) {
            short8 hh, ll;
            #pragma unroll
            for (int jj = 0; jj < 8; ++jj) {
                const int kk = c * 32 + kq + jj;
                const float x = (kk < 80 && n < 40) ? W2[kk * 40 + n] : 0.f;
                unsigned short hi, lo; split2(x, hi, lo);
                hh[jj] = (short)hi; ll[jj] = (short)lo;
            }
            w2h[nt][c] = hh; w2l[nt][c] = ll;
        }
    }
    float wf3[3], b23[3], bb1[5];
    #pragma unroll
    for (int nt = 0; nt < 3; ++nt) {
        const int n = nt * 16 + ncl;
        wf3[nt] = (n < 40) ? Wf[n] : 0.f;
        b23[nt] = (n < 40) ? b2[n] : 0.f;
    }
    #pragma unroll
    for (int nt = 0; nt < 5; ++nt) {
        const int n = nt * 16 + ncl;
        bb1[nt] = b1[n] + s_b1p[n] + s_b1p[80 + n] + s_b1p[160 + n];
    }
    const float bfv = bf[0];

    // ---- barrier-free tile loop: wave wv owns m-tiles wv, wv+4, wv+8, wv+12
    const int h1row = (wv * 16 + ncl) * 104;
    for (int mt = wv; mt < 13; mt += 4) {
        // current-tile a1/a2 coefficient loads issued FIRST (L2-hot ~200cyc);
        // consumed in the epilogues below -> ~one MFMA pass of slack.
        float ca1[5][4];
        #pragma unroll
        for (int nt = 0; nt < 5; ++nt) {
            #pragma unroll
            for (int r = 0; r < 4; ++r) {
                int t = mt * 16 + q4 * 4 + r; if (t > T_ - 1) t = T_ - 1;
                ca1[nt][r] = a1[t * 80 + nt * 16 + ncl];
            }
        }
        float ca2[3][4];
        #pragma unroll
        for (int nt = 0; nt < 3; ++nt) {
            const int n2 = nt * 16 + ncl;
            #pragma unroll
            for (int r = 0; r < 4; ++r) {
                int t = mt * 16 + q4 * 4 + r; if (t > T_ - 1) t = T_ - 1;
                ca2[nt][r] = (n2 < 40) ? a2[t * 40 + n2] : 0.f;
            }
        }

        // consume prefetched k -> A-fragments (split bf16)
        const float a0v[8] = {pk0.x, pk0.y, pk0.z, pk0.w, pk1.x, pk1.y, pk1.z, pk1.w};
        const float a1v[8] = {pk2.x, pk2.y, pk2.z, pk2.w, pk3.x, pk3.y, pk3.z, pk3.w};
        short8 ahi0, alo0, ahi1, alo1;
        #pragma unroll
        for (int jj = 0; jj < 8; ++jj) {
            unsigned short h, l;
            split2(a0v[jj], h, l); ahi0[jj] = (short)h; alo0[jj] = (short)l;
            split2(a1v[jj], h, l); ahi1[jj] = (short)h; alo1[jj] = (short)l;
        }

        // issue next-tile k loads UNCONDITIONALLY (clamped row; the extra load
        // on the last iteration is a harmless L2 hit). Named scalars -> SSA.
        {
            int trow_n = (mt + 4) * 16 + ncl; if (trow_n > T_ - 1) trow_n = T_ - 1;
            const float4* kr = (const float4*)(kb + trow_n * 64);
            pk0 = kr[q4 * 2];     pk1 = kr[q4 * 2 + 1];
            pk2 = kr[8 + q4 * 2]; pk3 = kr[8 + q4 * 2 + 1];
        }

        // Dense1 MFMA + PReLU1 epilogue -> h1 (wave-local LDS round-trip)
        #pragma unroll
        for (int nt = 0; nt < 5; ++nt) {
            const int n = nt * 16 + ncl;
            const short8 bhi0 = *(const short8*)&s_wqhi[n * 72 + kq];
            const short8 bhi1 = *(const short8*)&s_wqhi[n * 72 + 32 + kq];
            const short8 blo0 = *(const short8*)&s_wqlo[n * 72 + kq];
            const short8 blo1 = *(const short8*)&s_wqlo[n * 72 + 32 + kq];
            f32x4 acc = {0.f, 0.f, 0.f, 0.f};
            acc = __builtin_amdgcn_mfma_f32_16x16x32_bf16(ahi0, blo0, acc, 0, 0, 0);
            acc = __builtin_amdgcn_mfma_f32_16x16x32_bf16(alo0, bhi0, acc, 0, 0, 0);
            acc = __builtin_amdgcn_mfma_f32_16x16x32_bf16(ahi1, blo1, acc, 0, 0, 0);
            acc = __builtin_amdgcn_mfma_f32_16x16x32_bf16(alo1, bhi1, acc, 0, 0, 0);
            acc = __builtin_amdgcn_mfma_f32_16x16x32_bf16(ahi0, bhi0, acc, 0, 0, 0);
            acc = __builtin_amdgcn_mfma_f32_16x16x32_bf16(ahi1, bhi1, acc, 0, 0, 0);
            #pragma unroll
            for (int r = 0; r < 4; ++r) {
                const int rloc = q4 * 4 + r;
                float x = acc[r] + bb1[nt];
                const float al = ca1[nt][r];
                x = x > 0.f ? x : al * x;
                unsigned short hi, lo; split2(x, hi, lo);
                s_h1hi[(wv * 16 + rloc) * 104 + n] = hi;
                s_h1lo[(wv * 16 + rloc) * 104 + n] = lo;
            }
        }

        // Dense2 MFMA (W2 frags in regs) + PReLU2*Wf epilogue -> logits
        short8 ah[3], al[3];
        #pragma unroll
        for (int c = 0; c < 3; ++c) {
            ah[c] = *(const short8*)&s_h1hi[h1row + c * 32 + kq];
            al[c] = *(const short8*)&s_h1lo[h1row + c * 32 + kq];
        }
        float part[4] = {0.f, 0.f, 0.f, 0.f};
        #pragma unroll
        for (int nt = 0; nt < 3; ++nt) {
            f32x4 acc = {0.f, 0.f, 0.f, 0.f};
            #pragma unroll
            for (int c = 0; c < 3; ++c) {
                acc = __builtin_amdgcn_mfma_f32_16x16x32_bf16(ah[c], w2l[nt][c], acc, 0, 0, 0);
                acc = __builtin_amdgcn_mfma_f32_16x16x32_bf16(al[c], w2h[nt][c], acc, 0, 0, 0);
                acc = __builtin_amdgcn_mfma_f32_16x16x32_bf16(ah[c], w2h[nt][c], acc, 0, 0, 0);
            }
            #pragma unroll
            for (int r = 0; r < 4; ++r) {
                float x = acc[r] + b23[nt];
                const float al2 = ca2[nt][r];
                x = x > 0.f ? x : al2 * x;
                part[r] += x * wf3[nt];
            }
        }
        #pragma unroll
        for (int r = 0; r < 4; ++r) {
            float p = part[r];
            p += __shfl_xor(p, 1, 64);
            p += __shfl_xor(p, 2, 64);
            p += __shfl_xor(p, 4, 64);
            p += __shfl_xor(p, 8, 64);
            part[r] = p;
        }
        if (ncl == 0) {
            #pragma unroll
            for (int r = 0; r < 4; ++r) {
                const int t = mt * 16 + q4 * 4 + r;
                if (t < T_) s_logits[t] = part[r] + bfv;
            }
        }
    }
    __syncthreads();   // logits complete; s_h1 dead -> scratch reuse OK

    // ---- softmax over 200 logits (wave shuffles, 2 barriers)
    float logit = -INFINITY;
    if (tid < T_) logit = s_logits[tid];
    float mred = logit;
    #pragma unroll
    for (int off = 1; off < 64; off <<= 1) mred = fmaxf(mred, __shfl_xor(mred, off, 64));
    if (lane == 0) u_red[wv] = mred;
    __syncthreads();
    const float mx = fmaxf(fmaxf(u_red[0], u_red[1]), fmaxf(u_red[2], u_red[3]));
    const float ew = (tid < T_) ? __expf(logit - mx) : 0.f;
    float ssum = ew;
    #pragma unroll
    for (int off = 1; off < 64; off <<= 1) ssum += __shfl_xor(ssum, off, 64);
    if (lane == 0) u_red[4 + wv] = ssum;
    __syncthreads();
    const float tot = (u_red[4] + u_red[5]) + (u_red[6] + u_red[7]);
    const float inv = 1.0f / tot;
    u_w[tid] = ew * inv;
    __syncthreads();

    // ---- out[b][d] = sum_t w_t * v[b][t][d]
    // fixed 13-trip unrolled loop: all 13 independent global loads can issue
    // together (single latency), u_w reads are LDS-hot. No cross-barrier state.
    const int c4 = tid & 15, g = tid >> 4;
    const float4* vb4 = (const float4*)vb;
    float4 acc4 = {0.f, 0.f, 0.f, 0.f};
    #pragma unroll
    for (int i = 0; i < 13; ++i) {
        const int t = g + i * 16;
        const int tc = (t > T_ - 1) ? (T_ - 1) : t;
        const float wt = (t < T_) ? u_w[t] : 0.f;
        const float4 vv = vb4[tc * 16 + c4];
        acc4.x += wt * vv.x; acc4.y += wt * vv.y;
        acc4.z += wt * vv.z; acc4.w += wt * vv.w;
    }
    u_acc[tid] = acc4;
    __syncthreads();
    if (tid < 64) {
        const float* uf = (const float*)u_acc;
        float s = 0.f;
        #pragma unroll
        for (int gg = 0; gg < 16; ++gg) s += uf[gg * 64 + tid];
        out[b * 64 + tid] = s;
    }
}

extern "C" void kernel_launch(void* const* d_in, const int* in_sizes, int n_in,
                              void* d_out, int out_size, void* d_ws, size_t ws_size,
                              hipStream_t stream) {
    const float* q  = (const float*)d_in[0];
    const float* k  = (const float*)d_in[1];
    const float* v  = (const float*)d_in[2];
    const float* W1 = (const float*)d_in[3];
    const float* b1 = (const float*)d_in[4];
    const float* a1 = (const float*)d_in[5];
    const float* W2 = (const float*)d_in[6];
    const float* b2 = (const float*)d_in[7];
    const float* a2 = (const float*)d_in[8];
    const float* Wf = (const float*)d_in[9];
    const float* bf = (const float*)d_in[10];
    float* out = (float*)d_out;

    hipLaunchKernelGGL(att_kernel, dim3(B_), dim3(256), 0, stream,
                       q, k, v, W1, b1, a1, W2, b2, a2, Wf, bf, out);
}

// Round 7
// 283.216 us; speedup vs baseline: 1.7172x; 1.0619x over previous
//
#include <hip/hip_runtime.h>
#include <math.h>

#define B_  2048
#define T_  200

typedef short short8 __attribute__((ext_vector_type(8)));
typedef float f32x4  __attribute__((ext_vector_type(4)));

__device__ __forceinline__ unsigned short f2bf_rne(float x) {
    unsigned u = __float_as_uint(x);
    unsigned r = u + 0x7FFFu + ((u >> 16) & 1u);
    return (unsigned short)(r >> 16);
}
__device__ __forceinline__ float bf2f(unsigned short h) {
    return __uint_as_float(((unsigned)h) << 16);
}
__device__ __forceinline__ void split2(float x, unsigned short& hi, unsigned short& lo) {
    hi = f2bf_rne(x); lo = f2bf_rne(x - bf2f(hi));
}

// One block (4 waves) per batch element b. Barrier-free 13-m-tile loop.
// R6 = R5 + prologue de-serialization:
//   - base1: fixed 22-trip unrolled loop (clamped idx, predicated add) ->
//     ~44 independent L2 loads, ONE latency instead of ~21 chained (runtime
//     bounds in R5 blocked unrolling -> ~6K cycle serial chain at barrier 2)
//   - k-pad zero + W2-frag build + wf3/b23/bfv (global-only deps) hoisted
//     BEFORE barrier 1 -> hide under q-load + first-tile k-prefetch latency
// Spill discipline unchanged: (256,2), loop-carried state = named scalars only.
__global__ __launch_bounds__(256, 2)
void att_kernel(const float* __restrict__ q,
                const float* __restrict__ k,
                const float* __restrict__ v,
                const float* __restrict__ W1,
                const float* __restrict__ b1,
                const float* __restrict__ a1,
                const float* __restrict__ W2,
                const float* __restrict__ b2,
                const float* __restrict__ a2,
                const float* __restrict__ Wf,
                const float* __restrict__ bf,
                float* __restrict__ out)
{
    const int b    = blockIdx.x;
    const int tid  = threadIdx.x;
    const int lane = tid & 63;
    const int wv   = __builtin_amdgcn_readfirstlane(tid >> 6);
    const int ncl  = lane & 15;
    const int q4   = lane >> 4;
    const int kq   = q4 * 8;

    __shared__ unsigned short s_wqhi[80 * 72];               // 11.5 KB
    __shared__ unsigned short s_wqlo[80 * 72];               // 11.5 KB
    __shared__ __align__(16) unsigned short s_h1[2 * 64 * 104]; // 26 KB, unioned
    __shared__ float s_q[64];
    __shared__ float s_b1p[240];                             // base1 partials
    __shared__ float s_logits[256];

    unsigned short* s_h1hi = s_h1;
    unsigned short* s_h1lo = s_h1 + 64 * 104;
    // softmax/v-sum scratch aliases s_h1 (dead after the tile loop):
    float*  u_w   = (float*)s_h1;                 // [256]  bytes 0..1023
    float4* u_acc = (float4*)(s_h1 + 512);        // [256]  bytes 1024..5119
    float*  u_red = (float*)(s_h1 + 2560);        // [8]    bytes 5120..5151

    const float* kb = k + (size_t)b * T_ * 64;
    const float* vb = v + (size_t)b * T_ * 64;

    // ---- first-tile k prefetch (HBM-cold): issued first; everything below
    // up to the first consume runs in its shadow. mt = wv < 4 -> trow < 64.
    float4 pk0, pk1, pk2, pk3;
    {
        const float4* kr = (const float4*)(kb + (wv * 16 + ncl) * 64);
        pk0 = kr[q4 * 2];     pk1 = kr[q4 * 2 + 1];
        pk2 = kr[8 + q4 * 2]; pk3 = kr[8 + q4 * 2 + 1];
    }

    if (tid < 64) s_q[tid] = q[b * 64 + tid];

    // ---- global-only prologue work, BEFORE barrier 1 (hides under q/k loads)
    for (int idx = tid; idx < 1024; idx += 256) {   // zero h1 cols 80..95 (K-pad)
        const int r = idx >> 4, c = 80 + (idx & 15);
        s_h1hi[r * 104 + c] = 0;
        s_h1lo[r * 104 + c] = 0;
    }
    // W2 B-fragments into registers (built from L2, once per block)
    short8 w2h[3][3], w2l[3][3];
    #pragma unroll
    for (int nt = 0; nt < 3; ++nt) {
        const int n = nt * 16 + ncl;
        #pragma unroll
        for (int c = 0; c < 3; ++c) {
            short8 hh, ll;
            #pragma unroll
            for (int jj = 0; jj < 8; ++jj) {
                const int kk = c * 32 + kq + jj;
                const float x = (kk < 80 && n < 40) ? W2[kk * 40 + n] : 0.f;
                unsigned short hi, lo; split2(x, hi, lo);
                hh[jj] = (short)hi; ll[jj] = (short)lo;
            }
            w2h[nt][c] = hh; w2l[nt][c] = ll;
        }
    }
    float wf3[3], b23[3];
    #pragma unroll
    for (int nt = 0; nt < 3; ++nt) {
        const int n = nt * 16 + ncl;
        wf3[nt] = (n < 40) ? Wf[n] : 0.f;
        b23[nt] = (n < 40) ? b2[n] : 0.f;
    }
    const float bfv = bf[0];

    __syncthreads();   // B1: s_q (and pad-zero) visible

    // ---- q-dependent prologue: per-b wq (split bf16, B-layout [j][kk]) + base1
    for (int idx = tid; idx < 5120; idx += 256) {
        const int kk = idx / 80, j = idx - kk * 80;
        const float x = W1[5120 + idx] - W1[10240 + idx] + s_q[kk] * W1[15360 + idx];
        unsigned short hi, lo; split2(x, hi, lo);
        s_wqhi[j * 72 + kk] = hi;
        s_wqlo[j * 72 + kk] = lo;
    }
    // base1 partials: 3 k-chunks of <=22, FIXED trip count -> fully unrolled,
    // all loads independent (clamped index, predicated contribution)
    if (tid < 240) {
        const int part = tid / 80;          // 0,1,2
        const int j    = tid - part * 80;
        const int k0   = part * 22;         // 0,22,44
        float s = 0.f;
        #pragma unroll
        for (int kk = 0; kk < 22; ++kk) {
            const int i  = k0 + kk;
            const int ic = (i < 64) ? i : 63;
            const float w = W1[ic * 80 + j] + W1[10240 + ic * 80 + j];
            s += (i < 64) ? s_q[ic] * w : 0.f;
        }
        s_b1p[tid] = s;
    }
    __syncthreads();   // B2: s_wq + s_b1p visible

    float bb1[5];
    #pragma unroll
    for (int nt = 0; nt < 5; ++nt) {
        const int n = nt * 16 + ncl;
        bb1[nt] = b1[n] + s_b1p[n] + s_b1p[80 + n] + s_b1p[160 + n];
    }

    // ---- barrier-free tile loop: wave wv owns m-tiles wv, wv+4, wv+8, wv+12
    const int h1row = (wv * 16 + ncl) * 104;
    for (int mt = wv; mt < 13; mt += 4) {
        // current-tile a1/a2 coefficient loads issued FIRST (L2-hot ~200cyc);
        // consumed in the epilogues below -> ~one MFMA pass of slack.
        float ca1[5][4];
        #pragma unroll
        for (int nt = 0; nt < 5; ++nt) {
            #pragma unroll
            for (int r = 0; r < 4; ++r) {
                int t = mt * 16 + q4 * 4 + r; if (t > T_ - 1) t = T_ - 1;
                ca1[nt][r] = a1[t * 80 + nt * 16 + ncl];
            }
        }
        float ca2[3][4];
        #pragma unroll
        for (int nt = 0; nt < 3; ++nt) {
            const int n2 = nt * 16 + ncl;
            #pragma unroll
            for (int r = 0; r < 4; ++r) {
                int t = mt * 16 + q4 * 4 + r; if (t > T_ - 1) t = T_ - 1;
                ca2[nt][r] = (n2 < 40) ? a2[t * 40 + n2] : 0.f;
            }
        }

        // consume prefetched k -> A-fragments (split bf16)
        const float a0v[8] = {pk0.x, pk0.y, pk0.z, pk0.w, pk1.x, pk1.y, pk1.z, pk1.w};
        const float a1v[8] = {pk2.x, pk2.y, pk2.z, pk2.w, pk3.x, pk3.y, pk3.z, pk3.w};
        short8 ahi0, alo0, ahi1, alo1;
        #pragma unroll
        for (int jj = 0; jj < 8; ++jj) {
            unsigned short h, l;
            split2(a0v[jj], h, l); ahi0[jj] = (short)h; alo0[jj] = (short)l;
            split2(a1v[jj], h, l); ahi1[jj] = (short)h; alo1[jj] = (short)l;
        }

        // issue next-tile k loads UNCONDITIONALLY (clamped row; the extra load
        // on the last iteration is a harmless L2 hit). Named scalars -> SSA.
        {
            int trow_n = (mt + 4) * 16 + ncl; if (trow_n > T_ - 1) trow_n = T_ - 1;
            const float4* kr = (const float4*)(kb + trow_n * 64);
            pk0 = kr[q4 * 2];     pk1 = kr[q4 * 2 + 1];
            pk2 = kr[8 + q4 * 2]; pk3 = kr[8 + q4 * 2 + 1];
        }

        // Dense1 MFMA + PReLU1 epilogue -> h1 (wave-local LDS round-trip)
        #pragma unroll
        for (int nt = 0; nt < 5; ++nt) {
            const int n = nt * 16 + ncl;
            const short8 bhi0 = *(const short8*)&s_wqhi[n * 72 + kq];
            const short8 bhi1 = *(const short8*)&s_wqhi[n * 72 + 32 + kq];
            const short8 blo0 = *(const short8*)&s_wqlo[n * 72 + kq];
            const short8 blo1 = *(const short8*)&s_wqlo[n * 72 + 32 + kq];
            f32x4 acc = {0.f, 0.f, 0.f, 0.f};
            acc = __builtin_amdgcn_mfma_f32_16x16x32_bf16(ahi0, blo0, acc, 0, 0, 0);
            acc = __builtin_amdgcn_mfma_f32_16x16x32_bf16(alo0, bhi0, acc, 0, 0, 0);
            acc = __builtin_amdgcn_mfma_f32_16x16x32_bf16(ahi1, blo1, acc, 0, 0, 0);
            acc = __builtin_amdgcn_mfma_f32_16x16x32_bf16(alo1, bhi1, acc, 0, 0, 0);
            acc = __builtin_amdgcn_mfma_f32_16x16x32_bf16(ahi0, bhi0, acc, 0, 0, 0);
            acc = __builtin_amdgcn_mfma_f32_16x16x32_bf16(ahi1, bhi1, acc, 0, 0, 0);
            #pragma unroll
            for (int r = 0; r < 4; ++r) {
                const int rloc = q4 * 4 + r;
                float x = acc[r] + bb1[nt];
                const float al = ca1[nt][r];
                x = x > 0.f ? x : al * x;
                unsigned short hi, lo; split2(x, hi, lo);
                s_h1hi[(wv * 16 + rloc) * 104 + n] = hi;
                s_h1lo[(wv * 16 + rloc) * 104 + n] = lo;
            }
        }

        // Dense2 MFMA (W2 frags in regs) + PReLU2*Wf epilogue -> logits
        short8 ah[3], al[3];
        #pragma unroll
        for (int c = 0; c < 3; ++c) {
            ah[c] = *(const short8*)&s_h1hi[h1row + c * 32 + kq];
            al[c] = *(const short8*)&s_h1lo[h1row + c * 32 + kq];
        }
        float part[4] = {0.f, 0.f, 0.f, 0.f};
        #pragma unroll
        for (int nt = 0; nt < 3; ++nt) {
            f32x4 acc = {0.f, 0.f, 0.f, 0.f};
            #pragma unroll
            for (int c = 0; c < 3; ++c) {
                acc = __builtin_amdgcn_mfma_f32_16x16x32_bf16(ah[c], w2l[nt][c], acc, 0, 0, 0);
                acc = __builtin_amdgcn_mfma_f32_16x16x32_bf16(al[c], w2h[nt][c], acc, 0, 0, 0);
                acc = __builtin_amdgcn_mfma_f32_16x16x32_bf16(ah[c], w2h[nt][c], acc, 0, 0, 0);
            }
            #pragma unroll
            for (int r = 0; r < 4; ++r) {
                float x = acc[r] + b23[nt];
                const float al2 = ca2[nt][r];
                x = x > 0.f ? x : al2 * x;
                part[r] += x * wf3[nt];
            }
        }
        #pragma unroll
        for (int r = 0; r < 4; ++r) {
            float p = part[r];
            p += __shfl_xor(p, 1, 64);
            p += __shfl_xor(p, 2, 64);
            p += __shfl_xor(p, 4, 64);
            p += __shfl_xor(p, 8, 64);
            part[r] = p;
        }
        if (ncl == 0) {
            #pragma unroll
            for (int r = 0; r < 4; ++r) {
                const int t = mt * 16 + q4 * 4 + r;
                if (t < T_) s_logits[t] = part[r] + bfv;
            }
        }
    }
    __syncthreads();   // logits complete; s_h1 dead -> scratch reuse OK

    // ---- softmax over 200 logits (wave shuffles, 2 barriers)
    float logit = -INFINITY;
    if (tid < T_) logit = s_logits[tid];
    float mred = logit;
    #pragma unroll
    for (int off = 1; off < 64; off <<= 1) mred = fmaxf(mred, __shfl_xor(mred, off, 64));
    if (lane == 0) u_red[wv] = mred;
    __syncthreads();
    const float mx = fmaxf(fmaxf(u_red[0], u_red[1]), fmaxf(u_red[2], u_red[3]));
    const float ew = (tid < T_) ? __expf(logit - mx) : 0.f;
    float ssum = ew;
    #pragma unroll
    for (int off = 1; off < 64; off <<= 1) ssum += __shfl_xor(ssum, off, 64);
    if (lane == 0) u_red[4 + wv] = ssum;
    __syncthreads();
    const float tot = (u_red[4] + u_red[5]) + (u_red[6] + u_red[7]);
    const float inv = 1.0f / tot;
    u_w[tid] = ew * inv;
    __syncthreads();

    // ---- out[b][d] = sum_t w_t * v[b][t][d]
    // fixed 13-trip unrolled loop: all 13 independent global loads can issue
    // together (single latency), u_w reads are LDS-hot. No cross-barrier state.
    const int c4 = tid & 15, g = tid >> 4;
    const float4* vb4 = (const float4*)vb;
    float4 acc4 = {0.f, 0.f, 0.f, 0.f};
    #pragma unroll
    for (int i = 0; i < 13; ++i) {
        const int t = g + i * 16;
        const int tc = (t > T_ - 1) ? (T_ - 1) : t;
        const float wt = (t < T_) ? u_w[t] : 0.f;
        const float4 vv = vb4[tc * 16 + c4];
        acc4.x += wt * vv.x; acc4.y += wt * vv.y;
        acc4.z += wt * vv.z; acc4.w += wt * vv.w;
    }
    u_acc[tid] = acc4;
    __syncthreads();
    if (tid < 64) {
        const float* uf = (const float*)u_acc;
        float s = 0.f;
        #pragma unroll
        for (int gg = 0; gg < 16; ++gg) s += uf[gg * 64 + tid];
        out[b * 64 + tid] = s;
    }
}

extern "C" void kernel_launch(void* const* d_in, const int* in_sizes, int n_in,
                              void* d_out, int out_size, void* d_ws, size_t ws_size,
                              hipStream_t stream) {
    const float* q  = (const float*)d_in[0];
    const float* k  = (const float*)d_in[1];
    const float* v  = (const float*)d_in[2];
    const float* W1 = (const float*)d_in[3];
    const float* b1 = (const float*)d_in[4];
    const float* a1 = (const float*)d_in[5];
    const float* W2 = (const float*)d_in[6];
    const float* b2 = (const float*)d_in[7];
    const float* a2 = (const float*)d_in[8];
    const float* Wf = (const float*)d_in[9];
    const float* bf = (const float*)d_in[10];
    float* out = (float*)d_out;

    hipLaunchKernelGGL(att_kernel, dim3(B_), dim3(256), 0, stream,
                       q, k, v, W1, b1, a1, W2, b2, a2, Wf, bf, out);
}